// Round 1
// baseline (216.805 us; speedup 1.0000x reference)
//
#include <hip/hip_runtime.h>
#include <hip/hip_bf16.h>

typedef __attribute__((ext_vector_type(8))) short bf16x8;
typedef __attribute__((ext_vector_type(4))) float f32x4;

#define B_SZ 2
#define S_SZ 2048
#define D_SZ 1024
#define H_SZ 16
#define HD_SZ 64

static __device__ __forceinline__ short f2bf(float f) {
    unsigned u = __builtin_bit_cast(unsigned, f);
    u += 0x7FFFu + ((u >> 16) & 1u);
    return (short)(u >> 16);
}

// ---------------- fp32 -> bf16 ----------------
__global__ __launch_bounds__(256) void k_f32_to_bf16(const float* __restrict__ in,
                                                     short* __restrict__ out, int n) {
    int i = (blockIdx.x * 256 + threadIdx.x) * 4;
    if (i >= n) return;
    float4 v = *reinterpret_cast<const float4*>(in + i);
    short4 o;
    o.x = f2bf(v.x); o.y = f2bf(v.y); o.z = f2bf(v.z); o.w = f2bf(v.w);
    *reinterpret_cast<short4*>(out + i) = o;
}

// ---------------- fp32 [K][N] -> bf16 [N][K] ----------------
__global__ __launch_bounds__(256) void k_transpose_w(const float* __restrict__ in,
                                                     short* __restrict__ out, int K, int N) {
    __shared__ float tile[32][33];
    int k0 = blockIdx.y * 32, n0 = blockIdx.x * 32;
    int tx = threadIdx.x, ty = threadIdx.y;  // (32, 8)
    #pragma unroll
    for (int i = 0; i < 4; ++i)
        tile[ty + i * 8][tx] = in[(size_t)(k0 + ty + i * 8) * N + n0 + tx];
    __syncthreads();
    #pragma unroll
    for (int i = 0; i < 4; ++i)
        out[(size_t)(n0 + ty + i * 8) * K + k0 + tx] = f2bf(tile[tx][ty + i * 8]);
}

// ---------------- QKV GEMM: Xb[4096][1024] x W1T[3072][1024]^T + bias ----------------
// writes Q/K/V in [B][H][S][64] bf16 layout
__global__ __launch_bounds__(256) void k_gemm_qkv(
    const short* __restrict__ A, const short* __restrict__ Bt,
    const float* __restrict__ bias,
    short* __restrict__ Qo, short* __restrict__ Ko, short* __restrict__ Vo) {
    constexpr int K = 1024;
    __shared__ short As[128][40];
    __shared__ short Bs[128][40];
    const int tid = threadIdx.x;
    const int lane = tid & 63;
    const int wid = tid >> 6;
    const int wm = wid >> 1, wn = wid & 1;
    const int lr = lane & 15, lc = lane >> 4;
    const int bn = blockIdx.x, bm = blockIdx.y;
    const size_t arow0 = (size_t)bm * 128;
    const size_t brow0 = (size_t)bn * 128;

    f32x4 acc[4][4];
    #pragma unroll
    for (int m = 0; m < 4; ++m)
        #pragma unroll
        for (int n = 0; n < 4; ++n)
            acc[m][n] = (f32x4){0.f, 0.f, 0.f, 0.f};

    for (int kt = 0; kt < K; kt += 32) {
        __syncthreads();
        #pragma unroll
        for (int i = 0; i < 2; ++i) {
            int idx = i * 256 + tid;
            int r = idx >> 2;
            int c = (idx & 3) << 3;
            *reinterpret_cast<bf16x8*>(&As[r][c]) =
                *reinterpret_cast<const bf16x8*>(&A[(arow0 + r) * K + kt + c]);
            *reinterpret_cast<bf16x8*>(&Bs[r][c]) =
                *reinterpret_cast<const bf16x8*>(&Bt[(brow0 + r) * K + kt + c]);
        }
        __syncthreads();
        bf16x8 af[4], bfr[4];
        #pragma unroll
        for (int m = 0; m < 4; ++m)
            af[m] = *reinterpret_cast<const bf16x8*>(&As[wm * 64 + m * 16 + lr][lc * 8]);
        #pragma unroll
        for (int n = 0; n < 4; ++n)
            bfr[n] = *reinterpret_cast<const bf16x8*>(&Bs[wn * 64 + n * 16 + lr][lc * 8]);
        #pragma unroll
        for (int m = 0; m < 4; ++m)
            #pragma unroll
            for (int n = 0; n < 4; ++n)
                acc[m][n] = __builtin_amdgcn_mfma_f32_16x16x32_bf16(af[m], bfr[n], acc[m][n], 0, 0, 0);
    }

    #pragma unroll
    for (int n = 0; n < 4; ++n) {
        const int col = bn * 128 + wn * 64 + n * 16 + lr;
        const float bv = bias[col];
        short* dst = (col < 1024) ? Qo : (col < 2048 ? Ko : Vo);
        const int dg = col & 1023;
        const int h = dg >> 6, dd = dg & 63;
        #pragma unroll
        for (int m = 0; m < 4; ++m) {
            #pragma unroll
            for (int r = 0; r < 4; ++r) {
                int grow = bm * 128 + wm * 64 + m * 16 + lc * 4 + r;
                int b = grow >> 11, s = grow & 2047;
                dst[(((size_t)(b * H_SZ + h)) * S_SZ + s) * HD_SZ + dd] = f2bf(acc[m][n][r] + bv);
            }
        }
    }
}

// ---------------- V [BH][S][64] -> VT [BH][64][S] ----------------
__global__ __launch_bounds__(256) void k_transpose_v(const short* __restrict__ V,
                                                     short* __restrict__ VT) {
    __shared__ short t[64][72];
    int bh = blockIdx.y;
    int s0 = blockIdx.x * 64;
    int tid = threadIdx.x;
    #pragma unroll
    for (int i = 0; i < 2; ++i) {
        int idx = i * 256 + tid;
        int r = idx >> 3, c = (idx & 7) * 8;
        *reinterpret_cast<bf16x8*>(&t[r][c]) =
            *reinterpret_cast<const bf16x8*>(&V[((size_t)bh * S_SZ + s0 + r) * HD_SZ + c]);
    }
    __syncthreads();
    #pragma unroll
    for (int i = 0; i < 2; ++i) {
        int idx = i * 256 + tid;
        int d = idx >> 3, c = (idx & 7) * 8;
        bf16x8 tv;
        #pragma unroll
        for (int j = 0; j < 8; ++j) tv[j] = t[c + j][d];
        *reinterpret_cast<bf16x8*>(&VT[((size_t)bh * HD_SZ + d) * S_SZ + s0 + c]) = tv;
    }
}

// ---------------- flash attention ----------------
// grid: (S/64, B*H). block 256 = 4 waves; wave w owns q rows [qt*64 + w*16, +16)
__global__ __launch_bounds__(256) void k_attn(const short* __restrict__ Q,
                                              const short* __restrict__ Kv,
                                              const short* __restrict__ VT,
                                              short* __restrict__ O) {
    __shared__ short Ks[64][72];
    __shared__ short Vs[64][72];
    __shared__ short Ps[4][16][72];
    const int bh = blockIdx.y;
    const int h = bh & 15;
    const int bb = bh >> 4;
    const int qt = blockIdx.x;
    const int tid = threadIdx.x;
    const int lane = tid & 63, w = tid >> 6;
    const int lr = lane & 15, lc = lane >> 4;
    const int qrow0 = qt * 64 + w * 16;
    const size_t base = (size_t)bh * S_SZ * HD_SZ;

    bf16x8 qf[2];
    #pragma unroll
    for (int c = 0; c < 2; ++c)
        qf[c] = *reinterpret_cast<const bf16x8*>(&Q[base + (size_t)(qrow0 + lr) * HD_SZ + c * 32 + lc * 8]);

    float m_run[4], l_run[4];
    f32x4 o_acc[4];
    #pragma unroll
    for (int r = 0; r < 4; ++r) { m_run[r] = -1e30f; l_run[r] = 0.f; }
    #pragma unroll
    for (int n = 0; n < 4; ++n) o_acc[n] = (f32x4){0.f, 0.f, 0.f, 0.f};

    const int q_abs = qrow0 + lc * 4;

    for (int kt = 0; kt <= qt; ++kt) {
        __syncthreads();
        #pragma unroll
        for (int i = 0; i < 2; ++i) {
            int idx = i * 256 + tid;
            int r = idx >> 3, c = (idx & 7) * 8;
            *reinterpret_cast<bf16x8*>(&Ks[r][c]) =
                *reinterpret_cast<const bf16x8*>(&Kv[base + (size_t)(kt * 64 + r) * HD_SZ + c]);
            *reinterpret_cast<bf16x8*>(&Vs[r][c]) =
                *reinterpret_cast<const bf16x8*>(&VT[base + (size_t)r * S_SZ + kt * 64 + c]);
        }
        __syncthreads();

        // S = Q K^T
        f32x4 sf[4];
        #pragma unroll
        for (int n = 0; n < 4; ++n) {
            f32x4 z = (f32x4){0.f, 0.f, 0.f, 0.f};
            #pragma unroll
            for (int c = 0; c < 2; ++c) {
                bf16x8 kf = *reinterpret_cast<const bf16x8*>(&Ks[n * 16 + lr][c * 32 + lc * 8]);
                z = __builtin_amdgcn_mfma_f32_16x16x32_bf16(qf[c], kf, z, 0, 0, 0);
            }
            sf[n] = z;
        }
        // scale + causal mask (exact reference semantics: w/8 then masked -> -10000)
        #pragma unroll
        for (int n = 0; n < 4; ++n) {
            int kcol = kt * 64 + n * 16 + lr;
            #pragma unroll
            for (int r = 0; r < 4; ++r) {
                float v = sf[n][r] * 0.125f;
                sf[n][r] = (kcol > q_abs + r) ? -10000.0f : v;
            }
        }
        // row max
        float tmax[4];
        #pragma unroll
        for (int r = 0; r < 4; ++r)
            tmax[r] = fmaxf(fmaxf(sf[0][r], sf[1][r]), fmaxf(sf[2][r], sf[3][r]));
        #pragma unroll
        for (int msk = 1; msk < 16; msk <<= 1)
            #pragma unroll
            for (int r = 0; r < 4; ++r)
                tmax[r] = fmaxf(tmax[r], __shfl_xor(tmax[r], msk));
        // online softmax update
        float corr[4];
        #pragma unroll
        for (int r = 0; r < 4; ++r) {
            float mn = fmaxf(m_run[r], tmax[r]);
            corr[r] = __expf(m_run[r] - mn);
            m_run[r] = mn;
        }
        float rsum[4] = {0.f, 0.f, 0.f, 0.f};
        #pragma unroll
        for (int n = 0; n < 4; ++n)
            #pragma unroll
            for (int r = 0; r < 4; ++r) {
                float p = __expf(sf[n][r] - m_run[r]);
                sf[n][r] = p;
                rsum[r] += p;
            }
        #pragma unroll
        for (int msk = 1; msk < 16; msk <<= 1)
            #pragma unroll
            for (int r = 0; r < 4; ++r)
                rsum[r] += __shfl_xor(rsum[r], msk);
        #pragma unroll
        for (int r = 0; r < 4; ++r)
            l_run[r] = l_run[r] * corr[r] + rsum[r];
        #pragma unroll
        for (int n = 0; n < 4; ++n)
            #pragma unroll
            for (int r = 0; r < 4; ++r)
                o_acc[n][r] *= corr[r];

        // P -> LDS (per-wave region), then PV via MFMA
        #pragma unroll
        for (int n = 0; n < 4; ++n)
            #pragma unroll
            for (int r = 0; r < 4; ++r)
                Ps[w][lc * 4 + r][n * 16 + lr] = f2bf(sf[n][r]);

        #pragma unroll
        for (int c = 0; c < 2; ++c) {
            bf16x8 pa = *reinterpret_cast<const bf16x8*>(&Ps[w][lr][c * 32 + lc * 8]);
            #pragma unroll
            for (int n = 0; n < 4; ++n) {
                bf16x8 vf = *reinterpret_cast<const bf16x8*>(&Vs[n * 16 + lr][c * 32 + lc * 8]);
                o_acc[n] = __builtin_amdgcn_mfma_f32_16x16x32_bf16(pa, vf, o_acc[n], 0, 0, 0);
            }
        }
    }

    // epilogue: O[b][s][h*64+d] bf16
    #pragma unroll
    for (int n = 0; n < 4; ++n) {
        #pragma unroll
        for (int r = 0; r < 4; ++r) {
            float v = o_acc[n][r] / l_run[r];
            int s = qrow0 + lc * 4 + r;
            O[((size_t)bb * S_SZ + s) * D_SZ + h * 64 + n * 16 + lr] = f2bf(v);
        }
    }
}

// ---------------- proj GEMM: O[4096][1024] x W2T[1024][1024]^T + bias -> fp32 out ----------------
__global__ __launch_bounds__(256) void k_gemm_proj(
    const short* __restrict__ A, const short* __restrict__ Bt,
    const float* __restrict__ bias, float* __restrict__ out) {
    constexpr int K = 1024;
    constexpr int N = 1024;
    __shared__ short As[128][40];
    __shared__ short Bs[128][40];
    const int tid = threadIdx.x;
    const int lane = tid & 63;
    const int wid = tid >> 6;
    const int wm = wid >> 1, wn = wid & 1;
    const int lr = lane & 15, lc = lane >> 4;
    const int bn = blockIdx.x, bm = blockIdx.y;
    const size_t arow0 = (size_t)bm * 128;
    const size_t brow0 = (size_t)bn * 128;

    f32x4 acc[4][4];
    #pragma unroll
    for (int m = 0; m < 4; ++m)
        #pragma unroll
        for (int n = 0; n < 4; ++n)
            acc[m][n] = (f32x4){0.f, 0.f, 0.f, 0.f};

    for (int kt = 0; kt < K; kt += 32) {
        __syncthreads();
        #pragma unroll
        for (int i = 0; i < 2; ++i) {
            int idx = i * 256 + tid;
            int r = idx >> 2;
            int c = (idx & 3) << 3;
            *reinterpret_cast<bf16x8*>(&As[r][c]) =
                *reinterpret_cast<const bf16x8*>(&A[(arow0 + r) * K + kt + c]);
            *reinterpret_cast<bf16x8*>(&Bs[r][c]) =
                *reinterpret_cast<const bf16x8*>(&Bt[(brow0 + r) * K + kt + c]);
        }
        __syncthreads();
        bf16x8 af[4], bfr[4];
        #pragma unroll
        for (int m = 0; m < 4; ++m)
            af[m] = *reinterpret_cast<const bf16x8*>(&As[wm * 64 + m * 16 + lr][lc * 8]);
        #pragma unroll
        for (int n = 0; n < 4; ++n)
            bfr[n] = *reinterpret_cast<const bf16x8*>(&Bs[wn * 64 + n * 16 + lr][lc * 8]);
        #pragma unroll
        for (int m = 0; m < 4; ++m)
            #pragma unroll
            for (int n = 0; n < 4; ++n)
                acc[m][n] = __builtin_amdgcn_mfma_f32_16x16x32_bf16(af[m], bfr[n], acc[m][n], 0, 0, 0);
    }

    #pragma unroll
    for (int n = 0; n < 4; ++n) {
        const int col = bn * 128 + wn * 64 + n * 16 + lr;
        const float bv = bias[col];
        #pragma unroll
        for (int m = 0; m < 4; ++m) {
            #pragma unroll
            for (int r = 0; r < 4; ++r) {
                int grow = bm * 128 + wm * 64 + m * 16 + lc * 4 + r;
                out[(size_t)grow * N + col] = acc[m][n][r] + bv;
            }
        }
    }
}

extern "C" void kernel_launch(void* const* d_in, const int* in_sizes, int n_in,
                              void* d_out, int out_size, void* d_ws, size_t ws_size,
                              hipStream_t stream) {
    (void)in_sizes; (void)n_in; (void)out_size; (void)ws_size;
    const float* hs     = (const float*)d_in[0];
    const float* w_attn = (const float*)d_in[1];
    const float* b_attn = (const float*)d_in[2];
    const float* w_proj = (const float*)d_in[3];
    const float* b_proj = (const float*)d_in[4];
    float* out = (float*)d_out;
    char* ws = (char*)d_ws;

    // workspace layout (bytes); VTb overlays Xb, Ob overlays Vb (dead by then)
    short* Xb  = (short*)(ws + 0);         // 8 MiB  [4096][1024] bf16
    short* W1T = (short*)(ws + 8388608);   // 6 MiB  [3072][1024] bf16
    short* W2T = (short*)(ws + 14680064);  // 2 MiB  [1024][1024] bf16
    short* Qb  = (short*)(ws + 16777216);  // 8 MiB  [B][H][S][64]
    short* Kb  = (short*)(ws + 25165824);  // 8 MiB
    short* Vb  = (short*)(ws + 33554432);  // 8 MiB
    short* VTb = (short*)(ws + 0);         // 8 MiB  [B][H][64][S]  (over Xb)
    short* Ob  = (short*)(ws + 33554432);  // 8 MiB  [B][S][1024]   (over Vb)

    k_f32_to_bf16<<<dim3(4096), dim3(256), 0, stream>>>(hs, Xb, 4194304);
    k_transpose_w<<<dim3(96, 32), dim3(32, 8), 0, stream>>>(w_attn, W1T, 1024, 3072);
    k_transpose_w<<<dim3(32, 32), dim3(32, 8), 0, stream>>>(w_proj, W2T, 1024, 1024);
    k_gemm_qkv<<<dim3(24, 32), dim3(256), 0, stream>>>(Xb, W1T, b_attn, Qb, Kb, Vb);
    k_transpose_v<<<dim3(32, 32), dim3(256), 0, stream>>>(Vb, VTb);
    k_attn<<<dim3(32, 32), dim3(256), 0, stream>>>(Qb, Kb, VTb, Ob);
    k_gemm_proj<<<dim3(8, 32), dim3(256), 0, stream>>>(Ob, W2T, b_proj, out);
}

// Round 2
// 174.171 us; speedup vs baseline: 1.2448x; 1.2448x over previous
//
#include <hip/hip_runtime.h>
#include <hip/hip_bf16.h>

typedef __attribute__((ext_vector_type(8))) short bf16x8;
typedef __attribute__((ext_vector_type(4))) float f32x4;

#define B_SZ 2
#define S_SZ 2048
#define D_SZ 1024
#define H_SZ 16
#define HD_SZ 64

static __device__ __forceinline__ short f2bf(float f) {
    unsigned u = __builtin_bit_cast(unsigned, f);
    u += 0x7FFFu + ((u >> 16) & 1u);
    return (short)(u >> 16);
}

// ---------------- fp32 -> bf16 ----------------
__global__ __launch_bounds__(256) void k_f32_to_bf16(const float* __restrict__ in,
                                                     short* __restrict__ out, int n) {
    int i = (blockIdx.x * 256 + threadIdx.x) * 4;
    if (i >= n) return;
    float4 v = *reinterpret_cast<const float4*>(in + i);
    short4 o;
    o.x = f2bf(v.x); o.y = f2bf(v.y); o.z = f2bf(v.z); o.w = f2bf(v.w);
    *reinterpret_cast<short4*>(out + i) = o;
}

// ---------------- fp32 [K][N] -> bf16 [N][K] ----------------
__global__ __launch_bounds__(256) void k_transpose_w(const float* __restrict__ in,
                                                     short* __restrict__ out, int K, int N) {
    __shared__ float tile[32][33];
    int k0 = blockIdx.y * 32, n0 = blockIdx.x * 32;
    int tx = threadIdx.x, ty = threadIdx.y;  // (32, 8)
    #pragma unroll
    for (int i = 0; i < 4; ++i)
        tile[ty + i * 8][tx] = in[(size_t)(k0 + ty + i * 8) * N + n0 + tx];
    __syncthreads();
    #pragma unroll
    for (int i = 0; i < 4; ++i)
        out[(size_t)(n0 + ty + i * 8) * K + k0 + tx] = f2bf(tile[tx][ty + i * 8]);
}

// ---------------- QKV GEMM: Xb[4096][1024] x W1T[3072][1024]^T + bias ----------------
__global__ __launch_bounds__(256) void k_gemm_qkv(
    const short* __restrict__ A, const short* __restrict__ Bt,
    const float* __restrict__ bias,
    short* __restrict__ Qo, short* __restrict__ Ko, short* __restrict__ Vo) {
    constexpr int K = 1024;
    __shared__ short As[128][40];
    __shared__ short Bs[128][40];
    const int tid = threadIdx.x;
    const int lane = tid & 63;
    const int wid = tid >> 6;
    const int wm = wid >> 1, wn = wid & 1;
    const int lr = lane & 15, lc = lane >> 4;
    const int bn = blockIdx.x, bm = blockIdx.y;
    const size_t arow0 = (size_t)bm * 128;
    const size_t brow0 = (size_t)bn * 128;

    f32x4 acc[4][4];
    #pragma unroll
    for (int m = 0; m < 4; ++m)
        #pragma unroll
        for (int n = 0; n < 4; ++n)
            acc[m][n] = (f32x4){0.f, 0.f, 0.f, 0.f};

    for (int kt = 0; kt < K; kt += 32) {
        __syncthreads();
        #pragma unroll
        for (int i = 0; i < 2; ++i) {
            int idx = i * 256 + tid;
            int r = idx >> 2;
            int c = (idx & 3) << 3;
            *reinterpret_cast<bf16x8*>(&As[r][c]) =
                *reinterpret_cast<const bf16x8*>(&A[(arow0 + r) * K + kt + c]);
            *reinterpret_cast<bf16x8*>(&Bs[r][c]) =
                *reinterpret_cast<const bf16x8*>(&Bt[(brow0 + r) * K + kt + c]);
        }
        __syncthreads();
        bf16x8 af[4], bfr[4];
        #pragma unroll
        for (int m = 0; m < 4; ++m)
            af[m] = *reinterpret_cast<const bf16x8*>(&As[wm * 64 + m * 16 + lr][lc * 8]);
        #pragma unroll
        for (int n = 0; n < 4; ++n)
            bfr[n] = *reinterpret_cast<const bf16x8*>(&Bs[wn * 64 + n * 16 + lr][lc * 8]);
        #pragma unroll
        for (int m = 0; m < 4; ++m)
            #pragma unroll
            for (int n = 0; n < 4; ++n)
                acc[m][n] = __builtin_amdgcn_mfma_f32_16x16x32_bf16(af[m], bfr[n], acc[m][n], 0, 0, 0);
    }

    #pragma unroll
    for (int n = 0; n < 4; ++n) {
        const int col = bn * 128 + wn * 64 + n * 16 + lr;
        const float bv = bias[col];
        short* dst = (col < 1024) ? Qo : (col < 2048 ? Ko : Vo);
        const int dg = col & 1023;
        const int h = dg >> 6, dd = dg & 63;
        #pragma unroll
        for (int m = 0; m < 4; ++m) {
            #pragma unroll
            for (int r = 0; r < 4; ++r) {
                int grow = bm * 128 + wm * 64 + m * 16 + lc * 4 + r;
                int b = grow >> 11, s = grow & 2047;
                dst[(((size_t)(b * H_SZ + h)) * S_SZ + s) * HD_SZ + dd] = f2bf(acc[m][n][r] + bv);
            }
        }
    }
}

// ---------------- V [BH][S][64] -> VT [BH][64][S] ----------------
__global__ __launch_bounds__(256) void k_transpose_v(const short* __restrict__ V,
                                                     short* __restrict__ VT) {
    __shared__ short t[64][72];
    int bh = blockIdx.y;
    int s0 = blockIdx.x * 64;
    int tid = threadIdx.x;
    #pragma unroll
    for (int i = 0; i < 2; ++i) {
        int idx = i * 256 + tid;
        int r = idx >> 3, c = (idx & 7) * 8;
        *reinterpret_cast<bf16x8*>(&t[r][c]) =
            *reinterpret_cast<const bf16x8*>(&V[((size_t)bh * S_SZ + s0 + r) * HD_SZ + c]);
    }
    __syncthreads();
    #pragma unroll
    for (int i = 0; i < 2; ++i) {
        int idx = i * 256 + tid;
        int d = idx >> 3, c = (idx & 7) * 8;
        bf16x8 tv;
        #pragma unroll
        for (int j = 0; j < 8; ++j) tv[j] = t[c + j][d];
        *reinterpret_cast<bf16x8*>(&VT[((size_t)bh * HD_SZ + d) * S_SZ + s0 + c]) = tv;
    }
}

// ---------------- flash attention, causal-paired + double-buffered ----------------
// grid: (16, B*H). Block handles q-tiles pair p: qt_lo=p, qt_hi=31-p (33 tile-units each).
// 4 waves; wave w owns rows [qt*64 + w*16, +16) of each q-tile.
__global__ __launch_bounds__(256) void k_attn(const short* __restrict__ Q,
                                              const short* __restrict__ Kv,
                                              const short* __restrict__ VT,
                                              short* __restrict__ O) {
    __shared__ short Ks[2][64][72];
    __shared__ short Vs[2][64][72];
    __shared__ short Ps[4][16][72];
    const int bh = blockIdx.y;
    const int h = bh & 15;
    const int bb = bh >> 4;
    const int qt_lo = blockIdx.x;
    const int qt_hi = 31 - qt_lo;
    const int tid = threadIdx.x;
    const int lane = tid & 63, w = tid >> 6;
    const int lr = lane & 15, lc = lane >> 4;
    const size_t base = (size_t)bh * S_SZ * HD_SZ;

    const int qrow_lo = qt_lo * 64 + w * 16;
    const int qrow_hi = qt_hi * 64 + w * 16;

    bf16x8 qf_lo[2], qf_hi[2];
    #pragma unroll
    for (int c = 0; c < 2; ++c) {
        qf_lo[c] = *reinterpret_cast<const bf16x8*>(&Q[base + (size_t)(qrow_lo + lr) * HD_SZ + c * 32 + lc * 8]);
        qf_hi[c] = *reinterpret_cast<const bf16x8*>(&Q[base + (size_t)(qrow_hi + lr) * HD_SZ + c * 32 + lc * 8]);
    }

    float m_lo[4], l_lo[4], m_hi[4], l_hi[4];
    f32x4 o_lo[4], o_hi[4];
    #pragma unroll
    for (int r = 0; r < 4; ++r) { m_lo[r] = -1e30f; l_lo[r] = 0.f; m_hi[r] = -1e30f; l_hi[r] = 0.f; }
    #pragma unroll
    for (int n = 0; n < 4; ++n) { o_lo[n] = (f32x4){0.f, 0.f, 0.f, 0.f}; o_hi[n] = (f32x4){0.f, 0.f, 0.f, 0.f}; }

    // staging: each thread owns 2 K-rows-parts + 2 V-rows-parts (16B each)
    const int sr0 = tid >> 3, sc0 = (tid & 7) * 8;          // i=0
    const int sr1 = (256 + tid) >> 3, sc1 = sc0;            // i=1
    bf16x8 kr0, kr1, vr0, vr1;

    auto LOADT = [&](int kt) {
        kr0 = *reinterpret_cast<const bf16x8*>(&Kv[base + (size_t)(kt * 64 + sr0) * HD_SZ + sc0]);
        kr1 = *reinterpret_cast<const bf16x8*>(&Kv[base + (size_t)(kt * 64 + sr1) * HD_SZ + sc1]);
        vr0 = *reinterpret_cast<const bf16x8*>(&VT[base + (size_t)sr0 * S_SZ + kt * 64 + sc0]);
        vr1 = *reinterpret_cast<const bf16x8*>(&VT[base + (size_t)sr1 * S_SZ + kt * 64 + sc1]);
    };
    auto WRITET = [&](int b) {
        *reinterpret_cast<bf16x8*>(&Ks[b][sr0][sc0]) = kr0;
        *reinterpret_cast<bf16x8*>(&Ks[b][sr1][sc1]) = kr1;
        *reinterpret_cast<bf16x8*>(&Vs[b][sr0][sc0]) = vr0;
        *reinterpret_cast<bf16x8*>(&Vs[b][sr1][sc1]) = vr1;
    };

    auto PROCESS = [&](int buf, int kt, bf16x8* qf, int qrow0, bool diag,
                       float* m_run, float* l_run, f32x4* o_acc) {
        const int q_abs = qrow0 + lc * 4;
        f32x4 sf[4];
        #pragma unroll
        for (int n = 0; n < 4; ++n) {
            f32x4 z = (f32x4){0.f, 0.f, 0.f, 0.f};
            #pragma unroll
            for (int c = 0; c < 2; ++c) {
                bf16x8 kf = *reinterpret_cast<const bf16x8*>(&Ks[buf][n * 16 + lr][c * 32 + lc * 8]);
                z = __builtin_amdgcn_mfma_f32_16x16x32_bf16(qf[c], kf, z, 0, 0, 0);
            }
            sf[n] = z;
        }
        if (diag) {
            #pragma unroll
            for (int n = 0; n < 4; ++n) {
                int kcol = kt * 64 + n * 16 + lr;
                #pragma unroll
                for (int r = 0; r < 4; ++r) {
                    float v = sf[n][r] * 0.125f;
                    sf[n][r] = (kcol > q_abs + r) ? -10000.0f : v;
                }
            }
        } else {
            #pragma unroll
            for (int n = 0; n < 4; ++n)
                #pragma unroll
                for (int r = 0; r < 4; ++r)
                    sf[n][r] *= 0.125f;
        }
        float tmax[4];
        #pragma unroll
        for (int r = 0; r < 4; ++r)
            tmax[r] = fmaxf(fmaxf(sf[0][r], sf[1][r]), fmaxf(sf[2][r], sf[3][r]));
        #pragma unroll
        for (int msk = 1; msk < 16; msk <<= 1)
            #pragma unroll
            for (int r = 0; r < 4; ++r)
                tmax[r] = fmaxf(tmax[r], __shfl_xor(tmax[r], msk));
        float corr[4];
        #pragma unroll
        for (int r = 0; r < 4; ++r) {
            float mn = fmaxf(m_run[r], tmax[r]);
            corr[r] = __expf(m_run[r] - mn);
            m_run[r] = mn;
        }
        float rsum[4] = {0.f, 0.f, 0.f, 0.f};
        #pragma unroll
        for (int n = 0; n < 4; ++n)
            #pragma unroll
            for (int r = 0; r < 4; ++r) {
                float p = __expf(sf[n][r] - m_run[r]);
                sf[n][r] = p;
                rsum[r] += p;
            }
        #pragma unroll
        for (int msk = 1; msk < 16; msk <<= 1)
            #pragma unroll
            for (int r = 0; r < 4; ++r)
                rsum[r] += __shfl_xor(rsum[r], msk);
        #pragma unroll
        for (int r = 0; r < 4; ++r)
            l_run[r] = l_run[r] * corr[r] + rsum[r];
        #pragma unroll
        for (int n = 0; n < 4; ++n)
            #pragma unroll
            for (int r = 0; r < 4; ++r)
                o_acc[n][r] *= corr[r];
        #pragma unroll
        for (int n = 0; n < 4; ++n)
            #pragma unroll
            for (int r = 0; r < 4; ++r)
                Ps[w][lc * 4 + r][n * 16 + lr] = f2bf(sf[n][r]);
        #pragma unroll
        for (int c = 0; c < 2; ++c) {
            bf16x8 pa = *reinterpret_cast<const bf16x8*>(&Ps[w][lr][c * 32 + lc * 8]);
            #pragma unroll
            for (int n = 0; n < 4; ++n) {
                bf16x8 vf = *reinterpret_cast<const bf16x8*>(&Vs[buf][n * 16 + lr][c * 32 + lc * 8]);
                o_acc[n] = __builtin_amdgcn_mfma_f32_16x16x32_bf16(pa, vf, o_acc[n], 0, 0, 0);
            }
        }
    };

    int cb = 0;
    LOADT(0);
    WRITET(0);
    __syncthreads();
    for (int kt = 0; kt <= qt_hi; ++kt) {
        const bool havenext = kt < qt_hi;
        if (havenext) LOADT(kt + 1);
        PROCESS(cb, kt, qf_hi, qrow_hi, kt == qt_hi, m_hi, l_hi, o_hi);
        if (kt <= qt_lo)
            PROCESS(cb, kt, qf_lo, qrow_lo, kt == qt_lo, m_lo, l_lo, o_lo);
        __syncthreads();
        if (havenext) WRITET(cb ^ 1);
        __syncthreads();
        cb ^= 1;
    }

    auto EPI = [&](int qrow0, float* l_run, f32x4* o_acc) {
        #pragma unroll
        for (int n = 0; n < 4; ++n) {
            #pragma unroll
            for (int r = 0; r < 4; ++r) {
                float v = o_acc[n][r] / l_run[r];
                int s = qrow0 + lc * 4 + r;
                O[((size_t)bb * S_SZ + s) * D_SZ + h * 64 + n * 16 + lr] = f2bf(v);
            }
        }
    };
    EPI(qrow_hi, l_hi, o_hi);
    EPI(qrow_lo, l_lo, o_lo);
}

// ---------------- proj GEMM: O[4096][1024] x W2T[1024][1024]^T + bias -> fp32 out ----------------
__global__ __launch_bounds__(256) void k_gemm_proj(
    const short* __restrict__ A, const short* __restrict__ Bt,
    const float* __restrict__ bias, float* __restrict__ out) {
    constexpr int K = 1024;
    constexpr int N = 1024;
    __shared__ short As[128][40];
    __shared__ short Bs[128][40];
    const int tid = threadIdx.x;
    const int lane = tid & 63;
    const int wid = tid >> 6;
    const int wm = wid >> 1, wn = wid & 1;
    const int lr = lane & 15, lc = lane >> 4;
    const int bn = blockIdx.x, bm = blockIdx.y;
    const size_t arow0 = (size_t)bm * 128;
    const size_t brow0 = (size_t)bn * 128;

    f32x4 acc[4][4];
    #pragma unroll
    for (int m = 0; m < 4; ++m)
        #pragma unroll
        for (int n = 0; n < 4; ++n)
            acc[m][n] = (f32x4){0.f, 0.f, 0.f, 0.f};

    for (int kt = 0; kt < K; kt += 32) {
        __syncthreads();
        #pragma unroll
        for (int i = 0; i < 2; ++i) {
            int idx = i * 256 + tid;
            int r = idx >> 2;
            int c = (idx & 3) << 3;
            *reinterpret_cast<bf16x8*>(&As[r][c]) =
                *reinterpret_cast<const bf16x8*>(&A[(arow0 + r) * K + kt + c]);
            *reinterpret_cast<bf16x8*>(&Bs[r][c]) =
                *reinterpret_cast<const bf16x8*>(&Bt[(brow0 + r) * K + kt + c]);
        }
        __syncthreads();
        bf16x8 af[4], bfr[4];
        #pragma unroll
        for (int m = 0; m < 4; ++m)
            af[m] = *reinterpret_cast<const bf16x8*>(&As[wm * 64 + m * 16 + lr][lc * 8]);
        #pragma unroll
        for (int n = 0; n < 4; ++n)
            bfr[n] = *reinterpret_cast<const bf16x8*>(&Bs[wn * 64 + n * 16 + lr][lc * 8]);
        #pragma unroll
        for (int m = 0; m < 4; ++m)
            #pragma unroll
            for (int n = 0; n < 4; ++n)
                acc[m][n] = __builtin_amdgcn_mfma_f32_16x16x32_bf16(af[m], bfr[n], acc[m][n], 0, 0, 0);
    }

    #pragma unroll
    for (int n = 0; n < 4; ++n) {
        const int col = bn * 128 + wn * 64 + n * 16 + lr;
        const float bv = bias[col];
        #pragma unroll
        for (int m = 0; m < 4; ++m) {
            #pragma unroll
            for (int r = 0; r < 4; ++r) {
                int grow = bm * 128 + wm * 64 + m * 16 + lc * 4 + r;
                out[(size_t)grow * N + col] = acc[m][n][r] + bv;
            }
        }
    }
}

extern "C" void kernel_launch(void* const* d_in, const int* in_sizes, int n_in,
                              void* d_out, int out_size, void* d_ws, size_t ws_size,
                              hipStream_t stream) {
    (void)in_sizes; (void)n_in; (void)out_size; (void)ws_size;
    const float* hs     = (const float*)d_in[0];
    const float* w_attn = (const float*)d_in[1];
    const float* b_attn = (const float*)d_in[2];
    const float* w_proj = (const float*)d_in[3];
    const float* b_proj = (const float*)d_in[4];
    float* out = (float*)d_out;
    char* ws = (char*)d_ws;

    short* Xb  = (short*)(ws + 0);         // 8 MiB  [4096][1024] bf16
    short* W1T = (short*)(ws + 8388608);   // 6 MiB  [3072][1024] bf16
    short* W2T = (short*)(ws + 14680064);  // 2 MiB  [1024][1024] bf16
    short* Qb  = (short*)(ws + 16777216);  // 8 MiB  [B][H][S][64]
    short* Kb  = (short*)(ws + 25165824);  // 8 MiB
    short* Vb  = (short*)(ws + 33554432);  // 8 MiB
    short* VTb = (short*)(ws + 0);         // 8 MiB  [B][H][64][S]  (over Xb)
    short* Ob  = (short*)(ws + 33554432);  // 8 MiB  [B][S][1024]   (over Vb)

    k_f32_to_bf16<<<dim3(4096), dim3(256), 0, stream>>>(hs, Xb, 4194304);
    k_transpose_w<<<dim3(96, 32), dim3(32, 8), 0, stream>>>(w_attn, W1T, 1024, 3072);
    k_transpose_w<<<dim3(32, 32), dim3(32, 8), 0, stream>>>(w_proj, W2T, 1024, 1024);
    k_gemm_qkv<<<dim3(24, 32), dim3(256), 0, stream>>>(Xb, W1T, b_attn, Qb, Kb, Vb);
    k_transpose_v<<<dim3(32, 32), dim3(256), 0, stream>>>(Vb, VTb);
    k_attn<<<dim3(16, 32), dim3(256), 0, stream>>>(Qb, Kb, VTb, Ob);
    k_gemm_proj<<<dim3(8, 32), dim3(256), 0, stream>>>(Ob, W2T, b_proj, out);
}

// Round 3
// 170.510 us; speedup vs baseline: 1.2715x; 1.0215x over previous
//
#include <hip/hip_runtime.h>
#include <hip/hip_bf16.h>

typedef __attribute__((ext_vector_type(8))) short bf16x8;
typedef __attribute__((ext_vector_type(4))) float f32x4;

#define B_SZ 2
#define S_SZ 2048
#define D_SZ 1024
#define H_SZ 16
#define HD_SZ 64

static __device__ __forceinline__ short f2bf(float f) {
    unsigned u = __builtin_bit_cast(unsigned, f);
    u += 0x7FFFu + ((u >> 16) & 1u);
    return (short)(u >> 16);
}

static __device__ __forceinline__ void gload16(const short* g, short* l) {
    __builtin_amdgcn_global_load_lds(
        (const __attribute__((address_space(1))) unsigned*)g,
        (__attribute__((address_space(3))) unsigned*)l,
        16, 0, 0);
}

// ---------------- fp32 -> bf16 ----------------
__global__ __launch_bounds__(256) void k_f32_to_bf16(const float* __restrict__ in,
                                                     short* __restrict__ out, int n) {
    int i = (blockIdx.x * 256 + threadIdx.x) * 4;
    if (i >= n) return;
    float4 v = *reinterpret_cast<const float4*>(in + i);
    short4 o;
    o.x = f2bf(v.x); o.y = f2bf(v.y); o.z = f2bf(v.z); o.w = f2bf(v.w);
    *reinterpret_cast<short4*>(out + i) = o;
}

// ---------------- fp32 [K][N] -> bf16 [N][K] ----------------
__global__ __launch_bounds__(256) void k_transpose_w(const float* __restrict__ in,
                                                     short* __restrict__ out, int K, int N) {
    __shared__ float tile[32][33];
    int k0 = blockIdx.y * 32, n0 = blockIdx.x * 32;
    int tx = threadIdx.x, ty = threadIdx.y;  // (32, 8)
    #pragma unroll
    for (int i = 0; i < 4; ++i)
        tile[ty + i * 8][tx] = in[(size_t)(k0 + ty + i * 8) * N + n0 + tx];
    __syncthreads();
    #pragma unroll
    for (int i = 0; i < 4; ++i)
        out[(size_t)(n0 + ty + i * 8) * K + k0 + tx] = f2bf(tile[tx][ty + i * 8]);
}

// ---------------- QKV GEMM (m97 structure): Xb[4096][1024] x W1T[3072][1024]^T + bias ----------------
// writes Q (pre-scaled by 1/8) / K / V in [B][H][S][64] bf16 layout
__global__ __launch_bounds__(256) void k_gemm_qkv(
    const short* __restrict__ A, const short* __restrict__ Bt,
    const float* __restrict__ bias,
    short* __restrict__ Qo, short* __restrict__ Ko, short* __restrict__ Vo) {
    constexpr int K = 1024;
    __shared__ short As[128 * 64];
    __shared__ short Bs[128 * 64];
    const int tid = threadIdx.x;
    const int lane = tid & 63;
    const int w = tid >> 6;
    const int wm = w >> 1, wn = w & 1;
    const int lr = lane & 15, lc = lane >> 4;
    const int bn = blockIdx.x, bm = blockIdx.y;
    const size_t arow0 = (size_t)bm * 128;
    const size_t brow0 = (size_t)bn * 128;

    // staging addresses: chunk cid = w*4+i covers rows [cid*8, cid*8+8); lane covers 16B
    const short* aptr[4];
    const short* bptr[4];
    short* alds[4];
    short* blds[4];
    #pragma unroll
    for (int i = 0; i < 4; ++i) {
        int cid = w * 4 + i;
        int row = cid * 8 + (lane >> 3);
        int col = (lane & 7) * 8;
        aptr[i] = A + (arow0 + row) * K + col;
        bptr[i] = Bt + (brow0 + row) * K + col;
        alds[i] = &As[cid * 512];   // wave-uniform
        blds[i] = &Bs[cid * 512];
    }

    f32x4 acc[4][4];
    #pragma unroll
    for (int m = 0; m < 4; ++m)
        #pragma unroll
        for (int n = 0; n < 4; ++n)
            acc[m][n] = (f32x4){0.f, 0.f, 0.f, 0.f};

    for (int kt = 0; kt < K; kt += 64) {
        __syncthreads();
        #pragma unroll
        for (int i = 0; i < 4; ++i) {
            gload16(aptr[i] + kt, alds[i]);
            gload16(bptr[i] + kt, blds[i]);
        }
        __syncthreads();
        #pragma unroll
        for (int c = 0; c < 2; ++c) {
            bf16x8 af[4], bfr[4];
            #pragma unroll
            for (int m = 0; m < 4; ++m)
                af[m] = *reinterpret_cast<const bf16x8*>(&As[(wm * 64 + m * 16 + lr) * 64 + c * 32 + lc * 8]);
            #pragma unroll
            for (int n = 0; n < 4; ++n)
                bfr[n] = *reinterpret_cast<const bf16x8*>(&Bs[(wn * 64 + n * 16 + lr) * 64 + c * 32 + lc * 8]);
            #pragma unroll
            for (int m = 0; m < 4; ++m)
                #pragma unroll
                for (int n = 0; n < 4; ++n)
                    acc[m][n] = __builtin_amdgcn_mfma_f32_16x16x32_bf16(af[m], bfr[n], acc[m][n], 0, 0, 0);
        }
    }

    #pragma unroll
    for (int n = 0; n < 4; ++n) {
        const int col = bn * 128 + wn * 64 + n * 16 + lr;
        const float bv = bias[col];
        const bool isq = (col < 1024);
        const float scale = isq ? 0.125f : 1.0f;   // fold 1/sqrt(hd) into Q (exact: pow2)
        short* dst = isq ? Qo : (col < 2048 ? Ko : Vo);
        const int dg = col & 1023;
        const int h = dg >> 6, dd = dg & 63;
        #pragma unroll
        for (int m = 0; m < 4; ++m) {
            #pragma unroll
            for (int r = 0; r < 4; ++r) {
                int grow = bm * 128 + wm * 64 + m * 16 + lc * 4 + r;
                int b = grow >> 11, s = grow & 2047;
                dst[(((size_t)(b * H_SZ + h)) * S_SZ + s) * HD_SZ + dd] = f2bf((acc[m][n][r] + bv) * scale);
            }
        }
    }
}

// ---------------- V [BH][S][64] -> VT [BH][64][S] ----------------
__global__ __launch_bounds__(256) void k_transpose_v(const short* __restrict__ V,
                                                     short* __restrict__ VT) {
    __shared__ short t[64][72];
    int bh = blockIdx.y;
    int s0 = blockIdx.x * 64;
    int tid = threadIdx.x;
    #pragma unroll
    for (int i = 0; i < 2; ++i) {
        int idx = i * 256 + tid;
        int r = idx >> 3, c = (idx & 7) * 8;
        *reinterpret_cast<bf16x8*>(&t[r][c]) =
            *reinterpret_cast<const bf16x8*>(&V[((size_t)bh * S_SZ + s0 + r) * HD_SZ + c]);
    }
    __syncthreads();
    #pragma unroll
    for (int i = 0; i < 2; ++i) {
        int idx = i * 256 + tid;
        int d = idx >> 3, c = (idx & 7) * 8;
        bf16x8 tv;
        #pragma unroll
        for (int j = 0; j < 8; ++j) tv[j] = t[c + j][d];
        *reinterpret_cast<bf16x8*>(&VT[((size_t)bh * HD_SZ + d) * S_SZ + s0 + c]) = tv;
    }
}

// ---------------- flash attention, causal-paired + double-buffered + defer-max ----------------
__global__ __launch_bounds__(256) void k_attn(const short* __restrict__ Q,
                                              const short* __restrict__ Kv,
                                              const short* __restrict__ VT,
                                              short* __restrict__ O) {
    __shared__ short Ks[2][64][72];
    __shared__ short Vs[2][64][72];
    __shared__ short Ps[4][16][72];
    const int bh = blockIdx.y;
    const int h = bh & 15;
    const int bb = bh >> 4;
    const int qt_lo = blockIdx.x;
    const int qt_hi = 31 - qt_lo;
    const int tid = threadIdx.x;
    const int lane = tid & 63, w = tid >> 6;
    const int lr = lane & 15, lc = lane >> 4;
    const size_t base = (size_t)bh * S_SZ * HD_SZ;

    const int qrow_lo = qt_lo * 64 + w * 16;
    const int qrow_hi = qt_hi * 64 + w * 16;

    bf16x8 qf_lo[2], qf_hi[2];
    #pragma unroll
    for (int c = 0; c < 2; ++c) {
        qf_lo[c] = *reinterpret_cast<const bf16x8*>(&Q[base + (size_t)(qrow_lo + lr) * HD_SZ + c * 32 + lc * 8]);
        qf_hi[c] = *reinterpret_cast<const bf16x8*>(&Q[base + (size_t)(qrow_hi + lr) * HD_SZ + c * 32 + lc * 8]);
    }

    float m_lo[4], l_lo[4], m_hi[4], l_hi[4];
    f32x4 o_lo[4], o_hi[4];
    #pragma unroll
    for (int r = 0; r < 4; ++r) { m_lo[r] = -1e30f; l_lo[r] = 0.f; m_hi[r] = -1e30f; l_hi[r] = 0.f; }
    #pragma unroll
    for (int n = 0; n < 4; ++n) { o_lo[n] = (f32x4){0.f, 0.f, 0.f, 0.f}; o_hi[n] = (f32x4){0.f, 0.f, 0.f, 0.f}; }

    const int sr0 = tid >> 3, sc0 = (tid & 7) * 8;
    const int sr1 = (256 + tid) >> 3, sc1 = sc0;
    bf16x8 kr0, kr1, vr0, vr1;

    auto LOADT = [&](int kt) {
        kr0 = *reinterpret_cast<const bf16x8*>(&Kv[base + (size_t)(kt * 64 + sr0) * HD_SZ + sc0]);
        kr1 = *reinterpret_cast<const bf16x8*>(&Kv[base + (size_t)(kt * 64 + sr1) * HD_SZ + sc1]);
        vr0 = *reinterpret_cast<const bf16x8*>(&VT[base + (size_t)sr0 * S_SZ + kt * 64 + sc0]);
        vr1 = *reinterpret_cast<const bf16x8*>(&VT[base + (size_t)sr1 * S_SZ + kt * 64 + sc1]);
    };
    auto WRITET = [&](int b) {
        *reinterpret_cast<bf16x8*>(&Ks[b][sr0][sc0]) = kr0;
        *reinterpret_cast<bf16x8*>(&Ks[b][sr1][sc1]) = kr1;
        *reinterpret_cast<bf16x8*>(&Vs[b][sr0][sc0]) = vr0;
        *reinterpret_cast<bf16x8*>(&Vs[b][sr1][sc1]) = vr1;
    };

    auto PROCESS = [&](int buf, int kt, bf16x8* qf, int qrow0, bool diag,
                       float* m_run, float* l_run, f32x4* o_acc) {
        const int q_abs = qrow0 + lc * 4;
        f32x4 sf[4];
        #pragma unroll
        for (int n = 0; n < 4; ++n) {
            f32x4 z = (f32x4){0.f, 0.f, 0.f, 0.f};
            #pragma unroll
            for (int c = 0; c < 2; ++c) {
                bf16x8 kf = *reinterpret_cast<const bf16x8*>(&Ks[buf][n * 16 + lr][c * 32 + lc * 8]);
                z = __builtin_amdgcn_mfma_f32_16x16x32_bf16(qf[c], kf, z, 0, 0, 0);
            }
            sf[n] = z;
        }
        if (diag) {
            #pragma unroll
            for (int n = 0; n < 4; ++n) {
                int kcol = kt * 64 + n * 16 + lr;
                #pragma unroll
                for (int r = 0; r < 4; ++r)
                    sf[n][r] = (kcol > q_abs + r) ? -10000.0f : sf[n][r];
            }
        }
        float pmax[4];
        #pragma unroll
        for (int r = 0; r < 4; ++r)
            pmax[r] = fmaxf(fmaxf(sf[0][r], sf[1][r]), fmaxf(sf[2][r], sf[3][r]));
        #pragma unroll
        for (int msk = 1; msk < 16; msk <<= 1)
            #pragma unroll
            for (int r = 0; r < 4; ++r)
                pmax[r] = fmaxf(pmax[r], __shfl_xor(pmax[r], msk));
        // defer-max (T13): only rescale when some row's max grew past threshold
        bool need = (pmax[0] > m_run[0] + 8.f) | (pmax[1] > m_run[1] + 8.f) |
                    (pmax[2] > m_run[2] + 8.f) | (pmax[3] > m_run[3] + 8.f);
        if (__any(need)) {
            float corr[4];
            #pragma unroll
            for (int r = 0; r < 4; ++r) {
                float mn = fmaxf(m_run[r], pmax[r]);
                corr[r] = __expf(m_run[r] - mn);
                m_run[r] = mn;
                l_run[r] *= corr[r];
            }
            #pragma unroll
            for (int n = 0; n < 4; ++n)
                #pragma unroll
                for (int r = 0; r < 4; ++r)
                    o_acc[n][r] *= corr[r];
        }
        float rsum[4] = {0.f, 0.f, 0.f, 0.f};
        #pragma unroll
        for (int n = 0; n < 4; ++n)
            #pragma unroll
            for (int r = 0; r < 4; ++r) {
                float p = __expf(sf[n][r] - m_run[r]);
                sf[n][r] = p;
                rsum[r] += p;
            }
        #pragma unroll
        for (int msk = 1; msk < 16; msk <<= 1)
            #pragma unroll
            for (int r = 0; r < 4; ++r)
                rsum[r] += __shfl_xor(rsum[r], msk);
        #pragma unroll
        for (int r = 0; r < 4; ++r)
            l_run[r] += rsum[r];
        #pragma unroll
        for (int n = 0; n < 4; ++n)
            #pragma unroll
            for (int r = 0; r < 4; ++r)
                Ps[w][lc * 4 + r][n * 16 + lr] = f2bf(sf[n][r]);
        #pragma unroll
        for (int c = 0; c < 2; ++c) {
            bf16x8 pa = *reinterpret_cast<const bf16x8*>(&Ps[w][lr][c * 32 + lc * 8]);
            #pragma unroll
            for (int n = 0; n < 4; ++n) {
                bf16x8 vf = *reinterpret_cast<const bf16x8*>(&Vs[buf][n * 16 + lr][c * 32 + lc * 8]);
                o_acc[n] = __builtin_amdgcn_mfma_f32_16x16x32_bf16(pa, vf, o_acc[n], 0, 0, 0);
            }
        }
    };

    int cb = 0;
    LOADT(0);
    WRITET(0);
    __syncthreads();
    for (int kt = 0; kt <= qt_hi; ++kt) {
        const bool havenext = kt < qt_hi;
        if (havenext) LOADT(kt + 1);
        PROCESS(cb, kt, qf_hi, qrow_hi, kt == qt_hi, m_hi, l_hi, o_hi);
        if (kt <= qt_lo)
            PROCESS(cb, kt, qf_lo, qrow_lo, kt == qt_lo, m_lo, l_lo, o_lo);
        __syncthreads();
        if (havenext) WRITET(cb ^ 1);
        __syncthreads();
        cb ^= 1;
    }

    auto EPI = [&](int qrow0, float* l_run, f32x4* o_acc) {
        #pragma unroll
        for (int n = 0; n < 4; ++n) {
            #pragma unroll
            for (int r = 0; r < 4; ++r) {
                float v = o_acc[n][r] / l_run[r];
                int s = qrow0 + lc * 4 + r;
                O[((size_t)bb * S_SZ + s) * D_SZ + h * 64 + n * 16 + lr] = f2bf(v);
            }
        }
    };
    EPI(qrow_hi, l_hi, o_hi);
    EPI(qrow_lo, l_lo, o_lo);
}

// ---------------- proj GEMM (m97 structure): O[4096][1024] x W2T[1024][1024]^T + bias -> fp32 ----------------
__global__ __launch_bounds__(256) void k_gemm_proj(
    const short* __restrict__ A, const short* __restrict__ Bt,
    const float* __restrict__ bias, float* __restrict__ out) {
    constexpr int K = 1024;
    constexpr int N = 1024;
    __shared__ short As[128 * 64];
    __shared__ short Bs[128 * 64];
    const int tid = threadIdx.x;
    const int lane = tid & 63;
    const int w = tid >> 6;
    const int wm = w >> 1, wn = w & 1;
    const int lr = lane & 15, lc = lane >> 4;
    const int bn = blockIdx.x, bm = blockIdx.y;
    const size_t arow0 = (size_t)bm * 128;
    const size_t brow0 = (size_t)bn * 128;

    const short* aptr[4];
    const short* bptr[4];
    short* alds[4];
    short* blds[4];
    #pragma unroll
    for (int i = 0; i < 4; ++i) {
        int cid = w * 4 + i;
        int row = cid * 8 + (lane >> 3);
        int col = (lane & 7) * 8;
        aptr[i] = A + (arow0 + row) * K + col;
        bptr[i] = Bt + (brow0 + row) * K + col;
        alds[i] = &As[cid * 512];
        blds[i] = &Bs[cid * 512];
    }

    f32x4 acc[4][4];
    #pragma unroll
    for (int m = 0; m < 4; ++m)
        #pragma unroll
        for (int n = 0; n < 4; ++n)
            acc[m][n] = (f32x4){0.f, 0.f, 0.f, 0.f};

    for (int kt = 0; kt < K; kt += 64) {
        __syncthreads();
        #pragma unroll
        for (int i = 0; i < 4; ++i) {
            gload16(aptr[i] + kt, alds[i]);
            gload16(bptr[i] + kt, blds[i]);
        }
        __syncthreads();
        #pragma unroll
        for (int c = 0; c < 2; ++c) {
            bf16x8 af[4], bfr[4];
            #pragma unroll
            for (int m = 0; m < 4; ++m)
                af[m] = *reinterpret_cast<const bf16x8*>(&As[(wm * 64 + m * 16 + lr) * 64 + c * 32 + lc * 8]);
            #pragma unroll
            for (int n = 0; n < 4; ++n)
                bfr[n] = *reinterpret_cast<const bf16x8*>(&Bs[(wn * 64 + n * 16 + lr) * 64 + c * 32 + lc * 8]);
            #pragma unroll
            for (int m = 0; m < 4; ++m)
                #pragma unroll
                for (int n = 0; n < 4; ++n)
                    acc[m][n] = __builtin_amdgcn_mfma_f32_16x16x32_bf16(af[m], bfr[n], acc[m][n], 0, 0, 0);
        }
    }

    #pragma unroll
    for (int n = 0; n < 4; ++n) {
        const int col = bn * 128 + wn * 64 + n * 16 + lr;
        const float bv = bias[col];
        #pragma unroll
        for (int m = 0; m < 4; ++m) {
            #pragma unroll
            for (int r = 0; r < 4; ++r) {
                int grow = bm * 128 + wm * 64 + m * 16 + lc * 4 + r;
                out[(size_t)grow * N + col] = acc[m][n][r] + bv;
            }
        }
    }
}

extern "C" void kernel_launch(void* const* d_in, const int* in_sizes, int n_in,
                              void* d_out, int out_size, void* d_ws, size_t ws_size,
                              hipStream_t stream) {
    (void)in_sizes; (void)n_in; (void)out_size; (void)ws_size;
    const float* hs     = (const float*)d_in[0];
    const float* w_attn = (const float*)d_in[1];
    const float* b_attn = (const float*)d_in[2];
    const float* w_proj = (const float*)d_in[3];
    const float* b_proj = (const float*)d_in[4];
    float* out = (float*)d_out;
    char* ws = (char*)d_ws;

    short* Xb  = (short*)(ws + 0);         // 8 MiB  [4096][1024] bf16
    short* W1T = (short*)(ws + 8388608);   // 6 MiB  [3072][1024] bf16
    short* W2T = (short*)(ws + 14680064);  // 2 MiB  [1024][1024] bf16
    short* Qb  = (short*)(ws + 16777216);  // 8 MiB  [B][H][S][64] (pre-scaled by 1/8)
    short* Kb  = (short*)(ws + 25165824);  // 8 MiB
    short* Vb  = (short*)(ws + 33554432);  // 8 MiB
    short* VTb = (short*)(ws + 0);         // 8 MiB  [B][H][64][S]  (over Xb)
    short* Ob  = (short*)(ws + 33554432);  // 8 MiB  [B][S][1024]   (over Vb)

    k_f32_to_bf16<<<dim3(4096), dim3(256), 0, stream>>>(hs, Xb, 4194304);
    k_transpose_w<<<dim3(96, 32), dim3(32, 8), 0, stream>>>(w_attn, W1T, 1024, 3072);
    k_transpose_w<<<dim3(32, 32), dim3(32, 8), 0, stream>>>(w_proj, W2T, 1024, 1024);
    k_gemm_qkv<<<dim3(24, 32), dim3(256), 0, stream>>>(Xb, W1T, b_attn, Qb, Kb, Vb);
    k_transpose_v<<<dim3(32, 32), dim3(256), 0, stream>>>(Vb, VTb);
    k_attn<<<dim3(16, 32), dim3(256), 0, stream>>>(Qb, Kb, VTb, Ob);
    k_gemm_proj<<<dim3(8, 32), dim3(256), 0, stream>>>(Ob, W2T, b_proj, out);
}

// Round 4
// 166.423 us; speedup vs baseline: 1.3027x; 1.0246x over previous
//
#include <hip/hip_runtime.h>
#include <hip/hip_bf16.h>

typedef __attribute__((ext_vector_type(8))) short bf16x8;
typedef __attribute__((ext_vector_type(4))) float f32x4;

#define B_SZ 2
#define S_SZ 2048
#define D_SZ 1024
#define H_SZ 16
#define HD_SZ 64

static __device__ __forceinline__ short f2bf(float f) {
    unsigned u = __builtin_bit_cast(unsigned, f);
    u += 0x7FFFu + ((u >> 16) & 1u);
    return (short)(u >> 16);
}

static __device__ __forceinline__ void gload16(const short* g, short* l) {
    __builtin_amdgcn_global_load_lds(
        (const __attribute__((address_space(1))) unsigned*)g,
        (__attribute__((address_space(3))) unsigned*)l,
        16, 0, 0);
}

// ---------------- fp32 -> bf16 ----------------
__global__ __launch_bounds__(256) void k_f32_to_bf16(const float* __restrict__ in,
                                                     short* __restrict__ out, int n) {
    int i = (blockIdx.x * 256 + threadIdx.x) * 4;
    if (i >= n) return;
    float4 v = *reinterpret_cast<const float4*>(in + i);
    short4 o;
    o.x = f2bf(v.x); o.y = f2bf(v.y); o.z = f2bf(v.z); o.w = f2bf(v.w);
    *reinterpret_cast<short4*>(out + i) = o;
}

// ---------------- fp32 [K][N] -> bf16 [N][K] ----------------
__global__ __launch_bounds__(256) void k_transpose_w(const float* __restrict__ in,
                                                     short* __restrict__ out, int K, int N) {
    __shared__ float tile[32][33];
    int k0 = blockIdx.y * 32, n0 = blockIdx.x * 32;
    int tx = threadIdx.x, ty = threadIdx.y;  // (32, 8)
    #pragma unroll
    for (int i = 0; i < 4; ++i)
        tile[ty + i * 8][tx] = in[(size_t)(k0 + ty + i * 8) * N + n0 + tx];
    __syncthreads();
    #pragma unroll
    for (int i = 0; i < 4; ++i)
        out[(size_t)(n0 + ty + i * 8) * K + k0 + tx] = f2bf(tile[tx][ty + i * 8]);
}

// ---------------- QKV GEMM (m97 structure): Xb[4096][1024] x W1T[3072][1024]^T + bias ----------------
// writes Q (pre-scaled by 1/8) / K / V in [B][H][S][64] bf16 layout
__global__ __launch_bounds__(256) void k_gemm_qkv(
    const short* __restrict__ A, const short* __restrict__ Bt,
    const float* __restrict__ bias,
    short* __restrict__ Qo, short* __restrict__ Ko, short* __restrict__ Vo) {
    constexpr int K = 1024;
    __shared__ short As[128 * 64];
    __shared__ short Bs[128 * 64];
    const int tid = threadIdx.x;
    const int lane = tid & 63;
    const int w = tid >> 6;
    const int wm = w >> 1, wn = w & 1;
    const int lr = lane & 15, lc = lane >> 4;
    const int bn = blockIdx.x, bm = blockIdx.y;
    const size_t arow0 = (size_t)bm * 128;
    const size_t brow0 = (size_t)bn * 128;

    const short* aptr[4];
    const short* bptr[4];
    short* alds[4];
    short* blds[4];
    #pragma unroll
    for (int i = 0; i < 4; ++i) {
        int cid = w * 4 + i;
        int row = cid * 8 + (lane >> 3);
        int col = (lane & 7) * 8;
        aptr[i] = A + (arow0 + row) * K + col;
        bptr[i] = Bt + (brow0 + row) * K + col;
        alds[i] = &As[cid * 512];   // wave-uniform
        blds[i] = &Bs[cid * 512];
    }

    f32x4 acc[4][4];
    #pragma unroll
    for (int m = 0; m < 4; ++m)
        #pragma unroll
        for (int n = 0; n < 4; ++n)
            acc[m][n] = (f32x4){0.f, 0.f, 0.f, 0.f};

    for (int kt = 0; kt < K; kt += 64) {
        __syncthreads();
        #pragma unroll
        for (int i = 0; i < 4; ++i) {
            gload16(aptr[i] + kt, alds[i]);
            gload16(bptr[i] + kt, blds[i]);
        }
        __syncthreads();
        #pragma unroll
        for (int c = 0; c < 2; ++c) {
            bf16x8 af[4], bfr[4];
            #pragma unroll
            for (int m = 0; m < 4; ++m)
                af[m] = *reinterpret_cast<const bf16x8*>(&As[(wm * 64 + m * 16 + lr) * 64 + c * 32 + lc * 8]);
            #pragma unroll
            for (int n = 0; n < 4; ++n)
                bfr[n] = *reinterpret_cast<const bf16x8*>(&Bs[(wn * 64 + n * 16 + lr) * 64 + c * 32 + lc * 8]);
            #pragma unroll
            for (int m = 0; m < 4; ++m)
                #pragma unroll
                for (int n = 0; n < 4; ++n)
                    acc[m][n] = __builtin_amdgcn_mfma_f32_16x16x32_bf16(af[m], bfr[n], acc[m][n], 0, 0, 0);
        }
    }

    #pragma unroll
    for (int n = 0; n < 4; ++n) {
        const int col = bn * 128 + wn * 64 + n * 16 + lr;
        const float bv = bias[col];
        const bool isq = (col < 1024);
        const float scale = isq ? 0.125f : 1.0f;   // fold 1/sqrt(hd) into Q (exact: pow2)
        short* dst = isq ? Qo : (col < 2048 ? Ko : Vo);
        const int dg = col & 1023;
        const int h = dg >> 6, dd = dg & 63;
        #pragma unroll
        for (int m = 0; m < 4; ++m) {
            #pragma unroll
            for (int r = 0; r < 4; ++r) {
                int grow = bm * 128 + wm * 64 + m * 16 + lc * 4 + r;
                int b = grow >> 11, s = grow & 2047;
                dst[(((size_t)(b * H_SZ + h)) * S_SZ + s) * HD_SZ + dd] = f2bf((acc[m][n][r] + bv) * scale);
            }
        }
    }
}

// ---------------- V [BH][S][64] -> VT [BH][64][S] ----------------
__global__ __launch_bounds__(256) void k_transpose_v(const short* __restrict__ V,
                                                     short* __restrict__ VT) {
    __shared__ short t[64][72];
    int bh = blockIdx.y;
    int s0 = blockIdx.x * 64;
    int tid = threadIdx.x;
    #pragma unroll
    for (int i = 0; i < 2; ++i) {
        int idx = i * 256 + tid;
        int r = idx >> 3, c = (idx & 7) * 8;
        *reinterpret_cast<bf16x8*>(&t[r][c]) =
            *reinterpret_cast<const bf16x8*>(&V[((size_t)bh * S_SZ + s0 + r) * HD_SZ + c]);
    }
    __syncthreads();
    #pragma unroll
    for (int i = 0; i < 2; ++i) {
        int idx = i * 256 + tid;
        int d = idx >> 3, c = (idx & 7) * 8;
        bf16x8 tv;
        #pragma unroll
        for (int j = 0; j < 8; ++j) tv[j] = t[c + j][d];
        *reinterpret_cast<bf16x8*>(&VT[((size_t)bh * HD_SZ + d) * S_SZ + s0 + c]) = tv;
    }
}

// ---------------- flash attention: causal-paired, 8 waves, wave-split hi/lo ----------------
// grid (16, 32), block 512. Waves 0-3 own q-tile (31-p), waves 4-7 own q-tile p.
// Single-buffer K/V LDS + register prefetch. Q pre-scaled by 1/8.
__global__ __launch_bounds__(512) void k_attn(const short* __restrict__ Q,
                                              const short* __restrict__ Kv,
                                              const short* __restrict__ VT,
                                              short* __restrict__ O) {
    __shared__ short Ks[64][72];
    __shared__ short Vs[64][72];
    __shared__ short Ps[8][16][72];
    const int bh = blockIdx.y;
    const int h = bh & 15;
    const int bb = bh >> 4;
    const int qt_lo = blockIdx.x;
    const int qt_hi = 31 - qt_lo;
    const int tid = threadIdx.x;
    const int lane = tid & 63, w = tid >> 6;        // w 0..7
    const int lr = lane & 15, lc = lane >> 4;
    const bool isHi = (w < 4);
    const int myqt = isHi ? qt_hi : qt_lo;
    const int qrow0 = myqt * 64 + (w & 3) * 16;
    const size_t base = (size_t)bh * S_SZ * HD_SZ;

    bf16x8 qf[2];
    #pragma unroll
    for (int c = 0; c < 2; ++c)
        qf[c] = *reinterpret_cast<const bf16x8*>(&Q[base + (size_t)(qrow0 + lr) * HD_SZ + c * 32 + lc * 8]);

    float m_run[4], l_run[4];
    f32x4 o_acc[4];
    #pragma unroll
    for (int r = 0; r < 4; ++r) { m_run[r] = -1e30f; l_run[r] = 0.f; }
    #pragma unroll
    for (int n = 0; n < 4; ++n) o_acc[n] = (f32x4){0.f, 0.f, 0.f, 0.f};

    // staging: 512 threads x 16B = one full 64x64 K tile + one V tile
    const int sr = tid >> 3, sc = (tid & 7) * 8;
    bf16x8 kr, vr;
    auto LOADT = [&](int kt) {
        kr = *reinterpret_cast<const bf16x8*>(&Kv[base + (size_t)(kt * 64 + sr) * HD_SZ + sc]);
        vr = *reinterpret_cast<const bf16x8*>(&VT[base + (size_t)sr * S_SZ + kt * 64 + sc]);
    };
    auto WRITET = [&]() {
        *reinterpret_cast<bf16x8*>(&Ks[sr][sc]) = kr;
        *reinterpret_cast<bf16x8*>(&Vs[sr][sc]) = vr;
    };

    const int q_abs = qrow0 + lc * 4;

    LOADT(0);
    WRITET();
    __syncthreads();
    for (int kt = 0; kt <= qt_hi; ++kt) {
        const bool havenext = kt < qt_hi;   // uniform
        if (havenext) LOADT(kt + 1);
        if (isHi || kt <= qt_lo) {
            const bool diag = (kt == myqt);
            f32x4 sf[4];
            #pragma unroll
            for (int n = 0; n < 4; ++n) {
                f32x4 z = (f32x4){0.f, 0.f, 0.f, 0.f};
                #pragma unroll
                for (int c = 0; c < 2; ++c) {
                    bf16x8 kf = *reinterpret_cast<const bf16x8*>(&Ks[n * 16 + lr][c * 32 + lc * 8]);
                    z = __builtin_amdgcn_mfma_f32_16x16x32_bf16(qf[c], kf, z, 0, 0, 0);
                }
                sf[n] = z;
            }
            if (diag) {
                #pragma unroll
                for (int n = 0; n < 4; ++n) {
                    int kcol = kt * 64 + n * 16 + lr;
                    #pragma unroll
                    for (int r = 0; r < 4; ++r)
                        sf[n][r] = (kcol > q_abs + r) ? -10000.0f : sf[n][r];
                }
            }
            float pmax[4];
            #pragma unroll
            for (int r = 0; r < 4; ++r)
                pmax[r] = fmaxf(fmaxf(sf[0][r], sf[1][r]), fmaxf(sf[2][r], sf[3][r]));
            #pragma unroll
            for (int msk = 1; msk < 16; msk <<= 1)
                #pragma unroll
                for (int r = 0; r < 4; ++r)
                    pmax[r] = fmaxf(pmax[r], __shfl_xor(pmax[r], msk));
            bool need = (pmax[0] > m_run[0] + 8.f) | (pmax[1] > m_run[1] + 8.f) |
                        (pmax[2] > m_run[2] + 8.f) | (pmax[3] > m_run[3] + 8.f);
            if (__any(need)) {
                float corr[4];
                #pragma unroll
                for (int r = 0; r < 4; ++r) {
                    float mn = fmaxf(m_run[r], pmax[r]);
                    corr[r] = __expf(m_run[r] - mn);
                    m_run[r] = mn;
                    l_run[r] *= corr[r];
                }
                #pragma unroll
                for (int n = 0; n < 4; ++n)
                    #pragma unroll
                    for (int r = 0; r < 4; ++r)
                        o_acc[n][r] *= corr[r];
            }
            float rsum[4] = {0.f, 0.f, 0.f, 0.f};
            #pragma unroll
            for (int n = 0; n < 4; ++n)
                #pragma unroll
                for (int r = 0; r < 4; ++r) {
                    float pv = __expf(sf[n][r] - m_run[r]);
                    sf[n][r] = pv;
                    rsum[r] += pv;
                }
            #pragma unroll
            for (int msk = 1; msk < 16; msk <<= 1)
                #pragma unroll
                for (int r = 0; r < 4; ++r)
                    rsum[r] += __shfl_xor(rsum[r], msk);
            #pragma unroll
            for (int r = 0; r < 4; ++r)
                l_run[r] += rsum[r];
            #pragma unroll
            for (int n = 0; n < 4; ++n)
                #pragma unroll
                for (int r = 0; r < 4; ++r)
                    Ps[w][lc * 4 + r][n * 16 + lr] = f2bf(sf[n][r]);
            #pragma unroll
            for (int c = 0; c < 2; ++c) {
                bf16x8 pa = *reinterpret_cast<const bf16x8*>(&Ps[w][lr][c * 32 + lc * 8]);
                #pragma unroll
                for (int n = 0; n < 4; ++n) {
                    bf16x8 vf = *reinterpret_cast<const bf16x8*>(&Vs[n * 16 + lr][c * 32 + lc * 8]);
                    o_acc[n] = __builtin_amdgcn_mfma_f32_16x16x32_bf16(pa, vf, o_acc[n], 0, 0, 0);
                }
            }
        }
        if (havenext) {
            __syncthreads();   // all reads of Ks/Vs done
            WRITET();
            __syncthreads();   // new tile visible
        }
    }

    #pragma unroll
    for (int n = 0; n < 4; ++n) {
        #pragma unroll
        for (int r = 0; r < 4; ++r) {
            float v = o_acc[n][r] / l_run[r];
            int s = qrow0 + lc * 4 + r;
            O[((size_t)bb * S_SZ + s) * D_SZ + h * 64 + n * 16 + lr] = f2bf(v);
        }
    }
}

// ---------------- proj GEMM (m97 structure): O[4096][1024] x W2T[1024][1024]^T + bias -> fp32 ----------------
__global__ __launch_bounds__(256) void k_gemm_proj(
    const short* __restrict__ A, const short* __restrict__ Bt,
    const float* __restrict__ bias, float* __restrict__ out) {
    constexpr int K = 1024;
    constexpr int N = 1024;
    __shared__ short As[128 * 64];
    __shared__ short Bs[128 * 64];
    const int tid = threadIdx.x;
    const int lane = tid & 63;
    const int w = tid >> 6;
    const int wm = w >> 1, wn = w & 1;
    const int lr = lane & 15, lc = lane >> 4;
    const int bn = blockIdx.x, bm = blockIdx.y;
    const size_t arow0 = (size_t)bm * 128;
    const size_t brow0 = (size_t)bn * 128;

    const short* aptr[4];
    const short* bptr[4];
    short* alds[4];
    short* blds[4];
    #pragma unroll
    for (int i = 0; i < 4; ++i) {
        int cid = w * 4 + i;
        int row = cid * 8 + (lane >> 3);
        int col = (lane & 7) * 8;
        aptr[i] = A + (arow0 + row) * K + col;
        bptr[i] = Bt + (brow0 + row) * K + col;
        alds[i] = &As[cid * 512];
        blds[i] = &Bs[cid * 512];
    }

    f32x4 acc[4][4];
    #pragma unroll
    for (int m = 0; m < 4; ++m)
        #pragma unroll
        for (int n = 0; n < 4; ++n)
            acc[m][n] = (f32x4){0.f, 0.f, 0.f, 0.f};

    for (int kt = 0; kt < K; kt += 64) {
        __syncthreads();
        #pragma unroll
        for (int i = 0; i < 4; ++i) {
            gload16(aptr[i] + kt, alds[i]);
            gload16(bptr[i] + kt, blds[i]);
        }
        __syncthreads();
        #pragma unroll
        for (int c = 0; c < 2; ++c) {
            bf16x8 af[4], bfr[4];
            #pragma unroll
            for (int m = 0; m < 4; ++m)
                af[m] = *reinterpret_cast<const bf16x8*>(&As[(wm * 64 + m * 16 + lr) * 64 + c * 32 + lc * 8]);
            #pragma unroll
            for (int n = 0; n < 4; ++n)
                bfr[n] = *reinterpret_cast<const bf16x8*>(&Bs[(wn * 64 + n * 16 + lr) * 64 + c * 32 + lc * 8]);
            #pragma unroll
            for (int m = 0; m < 4; ++m)
                #pragma unroll
                for (int n = 0; n < 4; ++n)
                    acc[m][n] = __builtin_amdgcn_mfma_f32_16x16x32_bf16(af[m], bfr[n], acc[m][n], 0, 0, 0);
        }
    }

    #pragma unroll
    for (int n = 0; n < 4; ++n) {
        const int col = bn * 128 + wn * 64 + n * 16 + lr;
        const float bv = bias[col];
        #pragma unroll
        for (int m = 0; m < 4; ++m) {
            #pragma unroll
            for (int r = 0; r < 4; ++r) {
                int grow = bm * 128 + wm * 64 + m * 16 + lc * 4 + r;
                out[(size_t)grow * N + col] = acc[m][n][r] + bv;
            }
        }
    }
}

extern "C" void kernel_launch(void* const* d_in, const int* in_sizes, int n_in,
                              void* d_out, int out_size, void* d_ws, size_t ws_size,
                              hipStream_t stream) {
    (void)in_sizes; (void)n_in; (void)out_size; (void)ws_size;
    const float* hs     = (const float*)d_in[0];
    const float* w_attn = (const float*)d_in[1];
    const float* b_attn = (const float*)d_in[2];
    const float* w_proj = (const float*)d_in[3];
    const float* b_proj = (const float*)d_in[4];
    float* out = (float*)d_out;
    char* ws = (char*)d_ws;

    short* Xb  = (short*)(ws + 0);         // 8 MiB  [4096][1024] bf16
    short* W1T = (short*)(ws + 8388608);   // 6 MiB  [3072][1024] bf16
    short* W2T = (short*)(ws + 14680064);  // 2 MiB  [1024][1024] bf16
    short* Qb  = (short*)(ws + 16777216);  // 8 MiB  [B][H][S][64] (pre-scaled by 1/8)
    short* Kb  = (short*)(ws + 25165824);  // 8 MiB
    short* Vb  = (short*)(ws + 33554432);  // 8 MiB
    short* VTb = (short*)(ws + 0);         // 8 MiB  [B][H][64][S]  (over Xb)
    short* Ob  = (short*)(ws + 33554432);  // 8 MiB  [B][S][1024]   (over Vb)

    k_f32_to_bf16<<<dim3(4096), dim3(256), 0, stream>>>(hs, Xb, 4194304);
    k_transpose_w<<<dim3(96, 32), dim3(32, 8), 0, stream>>>(w_attn, W1T, 1024, 3072);
    k_transpose_w<<<dim3(32, 32), dim3(32, 8), 0, stream>>>(w_proj, W2T, 1024, 1024);
    k_gemm_qkv<<<dim3(24, 32), dim3(256), 0, stream>>>(Xb, W1T, b_attn, Qb, Kb, Vb);
    k_transpose_v<<<dim3(32, 32), dim3(256), 0, stream>>>(Vb, VTb);
    k_attn<<<dim3(16, 32), dim3(512), 0, stream>>>(Qb, Kb, VTb, Ob);
    k_gemm_proj<<<dim3(8, 32), dim3(256), 0, stream>>>(Ob, W2T, b_proj, out);
}

// Round 5
// 148.310 us; speedup vs baseline: 1.4618x; 1.1221x over previous
//
#include <hip/hip_runtime.h>
#include <hip/hip_bf16.h>

typedef __attribute__((ext_vector_type(8))) short bf16x8;
typedef __attribute__((ext_vector_type(4))) float f32x4;

#define B_SZ 2
#define S_SZ 2048
#define D_SZ 1024
#define H_SZ 16
#define HD_SZ 64

static __device__ __forceinline__ short f2bf(float f) {
    unsigned u = __builtin_bit_cast(unsigned, f);
    u += 0x7FFFu + ((u >> 16) & 1u);
    return (short)(u >> 16);
}

static __device__ __forceinline__ void gload16(const short* g, short* l) {
    __builtin_amdgcn_global_load_lds(
        (const __attribute__((address_space(1))) unsigned*)g,
        (__attribute__((address_space(3))) unsigned*)l,
        16, 0, 0);
}

// ---------------- fp32 -> bf16 ----------------
__global__ __launch_bounds__(256) void k_f32_to_bf16(const float* __restrict__ in,
                                                     short* __restrict__ out, int n) {
    int i = (blockIdx.x * 256 + threadIdx.x) * 4;
    if (i >= n) return;
    float4 v = *reinterpret_cast<const float4*>(in + i);
    short4 o;
    o.x = f2bf(v.x); o.y = f2bf(v.y); o.z = f2bf(v.z); o.w = f2bf(v.w);
    *reinterpret_cast<short4*>(out + i) = o;
}

// ---------------- fp32 [K][N] -> bf16 [N][K] ----------------
__global__ __launch_bounds__(256) void k_transpose_w(const float* __restrict__ in,
                                                     short* __restrict__ out, int K, int N) {
    __shared__ float tile[32][33];
    int k0 = blockIdx.y * 32, n0 = blockIdx.x * 32;
    int tx = threadIdx.x, ty = threadIdx.y;  // (32, 8)
    #pragma unroll
    for (int i = 0; i < 4; ++i)
        tile[ty + i * 8][tx] = in[(size_t)(k0 + ty + i * 8) * N + n0 + tx];
    __syncthreads();
    #pragma unroll
    for (int i = 0; i < 4; ++i)
        out[(size_t)(n0 + ty + i * 8) * K + k0 + tx] = f2bf(tile[tx][ty + i * 8]);
}

// ---------------- QKV GEMM (m97 structure): Xb[4096][1024] x W1T[3072][1024]^T + bias ----------------
// writes Q (pre-scaled by 1/8) / K / V in [B][H][S][64] bf16 layout
__global__ __launch_bounds__(256) void k_gemm_qkv(
    const short* __restrict__ A, const short* __restrict__ Bt,
    const float* __restrict__ bias,
    short* __restrict__ Qo, short* __restrict__ Ko, short* __restrict__ Vo) {
    constexpr int K = 1024;
    __shared__ short As[128 * 64];
    __shared__ short Bs[128 * 64];
    const int tid = threadIdx.x;
    const int lane = tid & 63;
    const int w = tid >> 6;
    const int wm = w >> 1, wn = w & 1;
    const int lr = lane & 15, lc = lane >> 4;
    const int bn = blockIdx.x, bm = blockIdx.y;
    const size_t arow0 = (size_t)bm * 128;
    const size_t brow0 = (size_t)bn * 128;

    const short* aptr[4];
    const short* bptr[4];
    short* alds[4];
    short* blds[4];
    #pragma unroll
    for (int i = 0; i < 4; ++i) {
        int cid = w * 4 + i;
        int row = cid * 8 + (lane >> 3);
        int col = (lane & 7) * 8;
        aptr[i] = A + (arow0 + row) * K + col;
        bptr[i] = Bt + (brow0 + row) * K + col;
        alds[i] = &As[cid * 512];   // wave-uniform
        blds[i] = &Bs[cid * 512];
    }

    f32x4 acc[4][4];
    #pragma unroll
    for (int m = 0; m < 4; ++m)
        #pragma unroll
        for (int n = 0; n < 4; ++n)
            acc[m][n] = (f32x4){0.f, 0.f, 0.f, 0.f};

    for (int kt = 0; kt < K; kt += 64) {
        __syncthreads();
        #pragma unroll
        for (int i = 0; i < 4; ++i) {
            gload16(aptr[i] + kt, alds[i]);
            gload16(bptr[i] + kt, blds[i]);
        }
        __syncthreads();
        #pragma unroll
        for (int c = 0; c < 2; ++c) {
            bf16x8 af[4], bfr[4];
            #pragma unroll
            for (int m = 0; m < 4; ++m)
                af[m] = *reinterpret_cast<const bf16x8*>(&As[(wm * 64 + m * 16 + lr) * 64 + c * 32 + lc * 8]);
            #pragma unroll
            for (int n = 0; n < 4; ++n)
                bfr[n] = *reinterpret_cast<const bf16x8*>(&Bs[(wn * 64 + n * 16 + lr) * 64 + c * 32 + lc * 8]);
            #pragma unroll
            for (int m = 0; m < 4; ++m)
                #pragma unroll
                for (int n = 0; n < 4; ++n)
                    acc[m][n] = __builtin_amdgcn_mfma_f32_16x16x32_bf16(af[m], bfr[n], acc[m][n], 0, 0, 0);
        }
    }

    #pragma unroll
    for (int n = 0; n < 4; ++n) {
        const int col = bn * 128 + wn * 64 + n * 16 + lr;
        const float bv = bias[col];
        const bool isq = (col < 1024);
        const float scale = isq ? 0.125f : 1.0f;   // fold 1/sqrt(hd) into Q (exact: pow2)
        short* dst = isq ? Qo : (col < 2048 ? Ko : Vo);
        const int dg = col & 1023;
        const int h = dg >> 6, dd = dg & 63;
        #pragma unroll
        for (int m = 0; m < 4; ++m) {
            #pragma unroll
            for (int r = 0; r < 4; ++r) {
                int grow = bm * 128 + wm * 64 + m * 16 + lc * 4 + r;
                int b = grow >> 11, s = grow & 2047;
                dst[(((size_t)(b * H_SZ + h)) * S_SZ + s) * HD_SZ + dd] = f2bf((acc[m][n][r] + bv) * scale);
            }
        }
    }
}

// ---------------- V [BH][S][64] -> VT [BH][64][S] ----------------
__global__ __launch_bounds__(256) void k_transpose_v(const short* __restrict__ V,
                                                     short* __restrict__ VT) {
    __shared__ short t[64][72];
    int bh = blockIdx.y;
    int s0 = blockIdx.x * 64;
    int tid = threadIdx.x;
    #pragma unroll
    for (int i = 0; i < 2; ++i) {
        int idx = i * 256 + tid;
        int r = idx >> 3, c = (idx & 7) * 8;
        *reinterpret_cast<bf16x8*>(&t[r][c]) =
            *reinterpret_cast<const bf16x8*>(&V[((size_t)bh * S_SZ + s0 + r) * HD_SZ + c]);
    }
    __syncthreads();
    #pragma unroll
    for (int i = 0; i < 2; ++i) {
        int idx = i * 256 + tid;
        int d = idx >> 3, c = (idx & 7) * 8;
        bf16x8 tv;
        #pragma unroll
        for (int j = 0; j < 8; ++j) tv[j] = t[c + j][d];
        *reinterpret_cast<bf16x8*>(&VT[((size_t)bh * HD_SZ + d) * S_SZ + s0 + c]) = tv;
    }
}

// ---------------- flash attention: causal-paired, 8 waves, swapped QK^T in-register softmax ----------------
// grid (16, 32), block 512. Waves 0-3 own q-tile (31-p), waves 4-7 own q-tile p.
// Q pre-scaled by 1/8. sf[n][r] = S[q=qrow0+lr][k=kt*64+n*16+lc*4+r] (S^T layout).
__global__ __launch_bounds__(512) void k_attn(const short* __restrict__ Q,
                                              const short* __restrict__ Kv,
                                              const short* __restrict__ VT,
                                              short* __restrict__ O) {
    __shared__ short Ks[64][72];
    __shared__ short Vs[64][72];
    __shared__ short Ps[8][16][72];
    const int bh = blockIdx.y;
    const int h = bh & 15;
    const int bb = bh >> 4;
    const int qt_lo = blockIdx.x;
    const int qt_hi = 31 - qt_lo;
    const int tid = threadIdx.x;
    const int lane = tid & 63, w = tid >> 6;        // w 0..7
    const int lr = lane & 15, lc = lane >> 4;
    const bool isHi = (w < 4);
    const int myqt = isHi ? qt_hi : qt_lo;
    const int qrow0 = myqt * 64 + (w & 3) * 16;
    const size_t base = (size_t)bh * S_SZ * HD_SZ;

    bf16x8 qf[2];
    #pragma unroll
    for (int c = 0; c < 2; ++c)
        qf[c] = *reinterpret_cast<const bf16x8*>(&Q[base + (size_t)(qrow0 + lr) * HD_SZ + c * 32 + lc * 8]);

    float m_run = -1e30f, l_run = 0.f;     // stats for q-row (qrow0 + lr)
    f32x4 o_acc[4];                         // O[q=lc*4+r][d=n*16+lr]
    #pragma unroll
    for (int n = 0; n < 4; ++n) o_acc[n] = (f32x4){0.f, 0.f, 0.f, 0.f};

    // staging: 512 threads x 16B = one full 64x64 K tile + one V tile
    const int sr = tid >> 3, sc = (tid & 7) * 8;
    bf16x8 kr, vr;
    auto LOADT = [&](int kt) {
        kr = *reinterpret_cast<const bf16x8*>(&Kv[base + (size_t)(kt * 64 + sr) * HD_SZ + sc]);
        vr = *reinterpret_cast<const bf16x8*>(&VT[base + (size_t)sr * S_SZ + kt * 64 + sc]);
    };
    auto WRITET = [&]() {
        *reinterpret_cast<bf16x8*>(&Ks[sr][sc]) = kr;
        *reinterpret_cast<bf16x8*>(&Vs[sr][sc]) = vr;
    };

    const int q_row = qrow0 + lr;

    LOADT(0);
    WRITET();
    __syncthreads();
    for (int kt = 0; kt <= qt_hi; ++kt) {
        const bool havenext = kt < qt_hi;   // uniform
        if (havenext) LOADT(kt + 1);
        if (isHi || kt <= qt_lo) {
            const bool diag = (kt == myqt);
            // S^T = K Q^T : swapped operands, same fragments
            f32x4 sf[4];
            #pragma unroll
            for (int n = 0; n < 4; ++n) {
                f32x4 z = (f32x4){0.f, 0.f, 0.f, 0.f};
                #pragma unroll
                for (int c = 0; c < 2; ++c) {
                    bf16x8 kf = *reinterpret_cast<const bf16x8*>(&Ks[n * 16 + lr][c * 32 + lc * 8]);
                    z = __builtin_amdgcn_mfma_f32_16x16x32_bf16(kf, qf[c], z, 0, 0, 0);
                }
                sf[n] = z;
            }
            if (diag) {
                const int kb = kt * 64 + lc * 4 - q_row;  // mask if kb + n*16 + r > 0
                #pragma unroll
                for (int n = 0; n < 4; ++n)
                    #pragma unroll
                    for (int r = 0; r < 4; ++r)
                        sf[n][r] = (kb + n * 16 + r > 0) ? -10000.0f : sf[n][r];
            }
            // row max: local tree over 16 regs + 2 cross-lc shuffles
            float pm01 = fmaxf(fmaxf(sf[0][0], sf[0][1]), fmaxf(sf[0][2], sf[0][3]));
            float pm23 = fmaxf(fmaxf(sf[1][0], sf[1][1]), fmaxf(sf[1][2], sf[1][3]));
            float pm45 = fmaxf(fmaxf(sf[2][0], sf[2][1]), fmaxf(sf[2][2], sf[2][3]));
            float pm67 = fmaxf(fmaxf(sf[3][0], sf[3][1]), fmaxf(sf[3][2], sf[3][3]));
            float pm = fmaxf(fmaxf(pm01, pm23), fmaxf(pm45, pm67));
            pm = fmaxf(pm, __shfl_xor(pm, 16));
            pm = fmaxf(pm, __shfl_xor(pm, 32));
            // defer-max (T13)
            if (__any(pm > m_run + 8.f)) {
                float mn = fmaxf(m_run, pm);
                float corr = __expf(m_run - mn);
                m_run = mn;
                l_run *= corr;
                float cr[4];
                #pragma unroll
                for (int r = 0; r < 4; ++r)
                    cr[r] = __shfl(corr, lc * 4 + r);   // corr for q-row lc*4+r
                #pragma unroll
                for (int n = 0; n < 4; ++n)
                    #pragma unroll
                    for (int r = 0; r < 4; ++r)
                        o_acc[n][r] *= cr[r];
            }
            // exp + row sum
            float rs = 0.f;
            #pragma unroll
            for (int n = 0; n < 4; ++n)
                #pragma unroll
                for (int r = 0; r < 4; ++r) {
                    float pv = __expf(sf[n][r] - m_run);
                    sf[n][r] = pv;
                    rs += pv;
                }
            rs += __shfl_xor(rs, 16);
            rs += __shfl_xor(rs, 32);
            l_run += rs;
            // P -> LDS: 4x ds_write_b64, k-contiguous per lane
            #pragma unroll
            for (int n = 0; n < 4; ++n) {
                short4 p4;
                p4.x = f2bf(sf[n][0]); p4.y = f2bf(sf[n][1]);
                p4.z = f2bf(sf[n][2]); p4.w = f2bf(sf[n][3]);
                *reinterpret_cast<short4*>(&Ps[w][lr][n * 16 + lc * 4]) = p4;
            }
            // PV
            #pragma unroll
            for (int c = 0; c < 2; ++c) {
                bf16x8 pa = *reinterpret_cast<const bf16x8*>(&Ps[w][lr][c * 32 + lc * 8]);
                #pragma unroll
                for (int n = 0; n < 4; ++n) {
                    bf16x8 vf = *reinterpret_cast<const bf16x8*>(&Vs[n * 16 + lr][c * 32 + lc * 8]);
                    o_acc[n] = __builtin_amdgcn_mfma_f32_16x16x32_bf16(pa, vf, o_acc[n], 0, 0, 0);
                }
            }
        }
        if (havenext) {
            __syncthreads();   // all reads of Ks/Vs done
            WRITET();
            __syncthreads();   // new tile visible
        }
    }

    // epilogue: l_run lives at q-row lr; o_acc rows are q=lc*4+r -> 4 bpermutes
    float li[4];
    #pragma unroll
    for (int r = 0; r < 4; ++r)
        li[r] = 1.0f / __shfl(l_run, lc * 4 + r);
    #pragma unroll
    for (int n = 0; n < 4; ++n) {
        #pragma unroll
        for (int r = 0; r < 4; ++r) {
            float v = o_acc[n][r] * li[r];
            int s = qrow0 + lc * 4 + r;
            O[((size_t)bb * S_SZ + s) * D_SZ + h * 64 + n * 16 + lr] = f2bf(v);
        }
    }
}

// ---------------- proj GEMM (m97 structure): O[4096][1024] x W2T[1024][1024]^T + bias -> fp32 ----------------
__global__ __launch_bounds__(256) void k_gemm_proj(
    const short* __restrict__ A, const short* __restrict__ Bt,
    const float* __restrict__ bias, float* __restrict__ out) {
    constexpr int K = 1024;
    constexpr int N = 1024;
    __shared__ short As[128 * 64];
    __shared__ short Bs[128 * 64];
    const int tid = threadIdx.x;
    const int lane = tid & 63;
    const int w = tid >> 6;
    const int wm = w >> 1, wn = w & 1;
    const int lr = lane & 15, lc = lane >> 4;
    const int bn = blockIdx.x, bm = blockIdx.y;
    const size_t arow0 = (size_t)bm * 128;
    const size_t brow0 = (size_t)bn * 128;

    const short* aptr[4];
    const short* bptr[4];
    short* alds[4];
    short* blds[4];
    #pragma unroll
    for (int i = 0; i < 4; ++i) {
        int cid = w * 4 + i;
        int row = cid * 8 + (lane >> 3);
        int col = (lane & 7) * 8;
        aptr[i] = A + (arow0 + row) * K + col;
        bptr[i] = Bt + (brow0 + row) * K + col;
        alds[i] = &As[cid * 512];
        blds[i] = &Bs[cid * 512];
    }

    f32x4 acc[4][4];
    #pragma unroll
    for (int m = 0; m < 4; ++m)
        #pragma unroll
        for (int n = 0; n < 4; ++n)
            acc[m][n] = (f32x4){0.f, 0.f, 0.f, 0.f};

    for (int kt = 0; kt < K; kt += 64) {
        __syncthreads();
        #pragma unroll
        for (int i = 0; i < 4; ++i) {
            gload16(aptr[i] + kt, alds[i]);
            gload16(bptr[i] + kt, blds[i]);
        }
        __syncthreads();
        #pragma unroll
        for (int c = 0; c < 2; ++c) {
            bf16x8 af[4], bfr[4];
            #pragma unroll
            for (int m = 0; m < 4; ++m)
                af[m] = *reinterpret_cast<const bf16x8*>(&As[(wm * 64 + m * 16 + lr) * 64 + c * 32 + lc * 8]);
            #pragma unroll
            for (int n = 0; n < 4; ++n)
                bfr[n] = *reinterpret_cast<const bf16x8*>(&Bs[(wn * 64 + n * 16 + lr) * 64 + c * 32 + lc * 8]);
            #pragma unroll
            for (int m = 0; m < 4; ++m)
                #pragma unroll
                for (int n = 0; n < 4; ++n)
                    acc[m][n] = __builtin_amdgcn_mfma_f32_16x16x32_bf16(af[m], bfr[n], acc[m][n], 0, 0, 0);
        }
    }

    #pragma unroll
    for (int n = 0; n < 4; ++n) {
        const int col = bn * 128 + wn * 64 + n * 16 + lr;
        const float bv = bias[col];
        #pragma unroll
        for (int m = 0; m < 4; ++m) {
            #pragma unroll
            for (int r = 0; r < 4; ++r) {
                int grow = bm * 128 + wm * 64 + m * 16 + lc * 4 + r;
                out[(size_t)grow * N + col] = acc[m][n][r] + bv;
            }
        }
    }
}

extern "C" void kernel_launch(void* const* d_in, const int* in_sizes, int n_in,
                              void* d_out, int out_size, void* d_ws, size_t ws_size,
                              hipStream_t stream) {
    (void)in_sizes; (void)n_in; (void)out_size; (void)ws_size;
    const float* hs     = (const float*)d_in[0];
    const float* w_attn = (const float*)d_in[1];
    const float* b_attn = (const float*)d_in[2];
    const float* w_proj = (const float*)d_in[3];
    const float* b_proj = (const float*)d_in[4];
    float* out = (float*)d_out;
    char* ws = (char*)d_ws;

    short* Xb  = (short*)(ws + 0);         // 8 MiB  [4096][1024] bf16
    short* W1T = (short*)(ws + 8388608);   // 6 MiB  [3072][1024] bf16
    short* W2T = (short*)(ws + 14680064);  // 2 MiB  [1024][1024] bf16
    short* Qb  = (short*)(ws + 16777216);  // 8 MiB  [B][H][S][64] (pre-scaled by 1/8)
    short* Kb  = (short*)(ws + 25165824);  // 8 MiB
    short* Vb  = (short*)(ws + 33554432);  // 8 MiB
    short* VTb = (short*)(ws + 0);         // 8 MiB  [B][H][64][S]  (over Xb)
    short* Ob  = (short*)(ws + 33554432);  // 8 MiB  [B][S][1024]   (over Vb)

    k_f32_to_bf16<<<dim3(4096), dim3(256), 0, stream>>>(hs, Xb, 4194304);
    k_transpose_w<<<dim3(96, 32), dim3(32, 8), 0, stream>>>(w_attn, W1T, 1024, 3072);
    k_transpose_w<<<dim3(32, 32), dim3(32, 8), 0, stream>>>(w_proj, W2T, 1024, 1024);
    k_gemm_qkv<<<dim3(24, 32), dim3(256), 0, stream>>>(Xb, W1T, b_attn, Qb, Kb, Vb);
    k_transpose_v<<<dim3(32, 32), dim3(256), 0, stream>>>(Vb, VTb);
    k_attn<<<dim3(16, 32), dim3(512), 0, stream>>>(Qb, Kb, VTb, Ob);
    k_gemm_proj<<<dim3(8, 32), dim3(256), 0, stream>>>(Ob, W2T, b_proj, out);
}